// Round 3
// baseline (861.576 us; speedup 1.0000x reference)
//
#include <hip/hip_runtime.h>
#include <math.h>

#define DI __device__ __forceinline__

constexpr int BB = 64;     // batch
constexpr int TT = 128;    // action steps (obs/rewards have TT+1)
constexpr int SS = 512;    // states
constexpr int AA = 16;     // actions
constexpr int OO = 4096;   // observations
constexpr float LOG2PI = 1.8378770664093453f;
constexpr float LOG4096 = 8.317766166719343f;  // log(16*256)

typedef float f32x4 __attribute__((ext_vector_type(4)));

// LDS-only barrier: drains LDS ops then barriers (does NOT drain vmcnt,
// so in-flight global fragment loads survive across it).
DI void lds_barrier() {
    asm volatile("s_waitcnt lgkmcnt(0)\n\ts_barrier" ::: "memory");
}

// ---------------- fp8 e4m3fn converter (RTNE), x in [0, 448) ----------------
DI unsigned int f32_to_e4m3(float x) {
    unsigned int u = __float_as_uint(x);
    unsigned int lsb = (u >> 20) & 1u;
    unsigned int rounded = u + 0x7ffffu + lsb;          // RTNE into 3-bit mantissa
    int e8 = (int)(rounded >> 23) - 120;                // 127 - 7
    unsigned int m3 = (rounded >> 20) & 7u;
    unsigned int norm = ((unsigned int)e8 << 3) | m3;
    int sub = __float2int_rn(x * 512.0f);               // subnormal: multiples of 2^-9
    return (e8 <= 0) ? (unsigned int)sub : norm;
}

// ---------------- reduction helpers (wave64) ----------------
DI float bflyMax(float v) {
#pragma unroll
    for (int off = 32; off; off >>= 1) v = fmaxf(v, __shfl_xor(v, off));
    return v;
}
DI float bflySum(float v) {
#pragma unroll
    for (int off = 32; off; off >>= 1) v += __shfl_xor(v, off);
    return v;
}
DI float halfMax(float v) {
#pragma unroll
    for (int off = 16; off; off >>= 1) v = fmaxf(v, __shfl_xor(v, off));
    return v;
}
DI float halfSum(float v) {
#pragma unroll
    for (int off = 16; off; off >>= 1) v += __shfl_xor(v, off);
    return v;
}

template <int NW>
DI float blockMax(float v, float* wr) {
    v = bflyMax(v);
    const int lane = threadIdx.x & 63, wv = threadIdx.x >> 6;
    if (lane == 0) wr[wv] = v;
    __syncthreads();
    float r = wr[0];
#pragma unroll
    for (int i = 1; i < NW; ++i) r = fmaxf(r, wr[i]);
    __syncthreads();
    return r;
}
template <int NW>
DI float blockSum(float v, float* wr) {
    v = bflySum(v);
    const int lane = threadIdx.x & 63, wv = threadIdx.x >> 6;
    if (lane == 0) wr[wv] = v;
    __syncthreads();
    float r = wr[0];
#pragma unroll
    for (int i = 1; i < NW; ++i) r += wr[i];
    __syncthreads();
    return r;
}

// ---------------- precompute kernels ----------------

// Fused softmax + fp8 quantize (x256) + MFMA-B-fragment swizzle (R3 layout).
// PB byte addr = (a*16 + kt)*16384 + ntp*1024 + lane*16 + (nt&1)*8 + j
// fragment byte j of (kt, nt, lane) = P[a][kt*32 + (lane>>4)*8 + j][nt*16 + (lane&15)]*256
__global__ __launch_bounds__(1024) void k_pack(const float* __restrict__ tl,
                                               unsigned char* __restrict__ PB) {
    __shared__ unsigned char lds[16384];
    const int a = blockIdx.x >> 4;
    const int kt = blockIdx.x & 15;
    const int tid = threadIdx.x;
    const int r = tid >> 5;       // 0..31
    const int nt = tid & 31;      // 0..31
    const int k = kt * 32 + r;
    const float* row = tl + ((size_t)a * SS + k) * SS + nt * 16;

    float x[16];
#pragma unroll
    for (int i = 0; i < 4; ++i) {
        float4 v = ((const float4*)row)[i];
        x[4 * i] = v.x; x[4 * i + 1] = v.y; x[4 * i + 2] = v.z; x[4 * i + 3] = v.w;
    }
    float mx = -INFINITY;
#pragma unroll
    for (int i = 0; i < 16; ++i) mx = fmaxf(mx, x[i]);
    mx = halfMax(mx);   // row lives in one 32-lane half
    float e[16];
    float sm = 0.f;
#pragma unroll
    for (int i = 0; i < 16; ++i) { e[i] = __expf(x[i] - mx); sm += e[i]; }
    sm = halfSum(sm);
    const float scale = 256.0f / sm;

    const int base = (nt >> 1) * 1024 + ((r >> 3) * 16) * 16 + (nt & 1) * 8 + (r & 7);
#pragma unroll
    for (int i = 0; i < 16; ++i) {
        lds[base + i * 16] = (unsigned char)f32_to_e4m3(e[i] * scale);
    }
    __syncthreads();

    ulonglong2* dst = (ulonglong2*)(PB + (size_t)(a * 16 + kt) * 16384);
    dst[tid] = ((const ulonglong2*)lds)[tid];
}

__global__ __launch_bounds__(256) void k_obs_stats(const float* __restrict__ ol,
                                                   float* __restrict__ mo,
                                                   float* __restrict__ lo) {
    __shared__ float wr[4];
    const int s = blockIdx.x;
    const float* in = ol + (size_t)s * OO;
    const int tid = threadIdx.x;
    float mx = -INFINITY;
    for (int i = tid; i < OO; i += 256) mx = fmaxf(mx, in[i]);
    float m = blockMax<4>(mx, wr);
    float sm = 0.f;
    for (int i = tid; i < OO; i += 256) sm += __expf(in[i] - m);
    float sum = blockSum<4>(sm, wr);
    if (tid == 0) { mo[s] = m; lo[s] = __logf(sum); }
}

__global__ __launch_bounds__(256) void k_obsT(const float* __restrict__ ol,
                                              const float* __restrict__ mo,
                                              const float* __restrict__ lo,
                                              float* __restrict__ obsT) {
    __shared__ float tile[64][65];
    const int tO = blockIdx.x % (OO / 64);
    const int tS = blockIdx.x / (OO / 64);
    const int o0 = tO * 64, s0 = tS * 64;
    const int cc = threadIdx.x & 63, rr = threadIdx.x >> 6;
#pragma unroll
    for (int j = 0; j < 16; ++j) {
        int r = rr + j * 4;
        tile[r][cc] = ol[(size_t)(s0 + r) * OO + o0 + cc] - mo[s0 + r] - lo[s0 + r];
    }
    __syncthreads();
#pragma unroll
    for (int j = 0; j < 16; ++j) {
        int r = rr + j * 4;
        obsT[(size_t)(o0 + r) * SS + s0 + cc] = tile[cc][r];
    }
}

// ---------------- main sequential-scan kernel (paired blocks) ----------------
// grid = 128: block (h = bid>>6, b = bid&63). Block h owns output states
// [256h, 256h+256). Each of 8 waves covers 32 output cols (one 1 KB fragment
// load per chunk -> 128 KB/step/CU, half of before). Per-step cross-block
// exchange of {256 p-bytes, m_blk, sum_blk} via agent-scope mailbox:
//   - each block quantizes its p-half with its OWN max (values <= 16, e4m3-safe);
//   - own-half chunks accumulate in accO*, partner half in accP*;
//   - combined post-MFMA with e^{mA-m}, e^{mB-m} -> exact same math.
// Wave 6 = publisher (relaxed payload stores + release flag; the release's
// vmcnt(0) only stalls wave 6). Wave 7 = receiver (acquire spin, lands
// partner bytes in LDS p8). Other waves overlap own-half MFMAs with the
// exchange; B3 (lds_barrier) gates partner-half MFMAs.
// Flag protocol: flag = t+1 (monotone, memset to 0 each launch); payload
// double-buffered by t&1. A overwrites slot t&1 at t+2 only after seeing
// flag_B >= t+2, which implies B finished step t+1 > read of slot t&1. Safe.
__global__ __launch_bounds__(512, 2) void k_main(
    const float* __restrict__ regime, const int* __restrict__ obs,
    const float* __restrict__ rewards, const float* __restrict__ dones,
    const int* __restrict__ actions, const float* __restrict__ prior_logits,
    const unsigned char* __restrict__ PB, const float* __restrict__ obsT,
    const float* __restrict__ policy_logits, const float* __restrict__ r_mu,
    const float* __restrict__ r_logsig, unsigned int* __restrict__ flags,
    char* __restrict__ mbox, float* __restrict__ out) {
    __shared__ float wrm[8], wrs[8];
    __shared__ float xsc[2];                    // partner (m, sum)
    __shared__ alignas(16) unsigned char p8[4 * 144 + 16];
    __shared__ float plds[SS];
    __shared__ int obs_l[TT + 1];
    __shared__ float rew_l[TT + 1];
    __shared__ float done_l[TT + 1];
    __shared__ int act_l[TT];

    const int bid = blockIdx.x;
    const int h = bid >> 6;        // half: 0 or 1
    const int b = bid & 63;        // batch
    const int tid = threadIdx.x;
    const int wv = tid >> 6, lane = tid & 63, quad = lane >> 4;
    const int KOWN = 8 * h;        // own chunk base (kt)
    const int KOTH = 8 * (1 - h);  // partner chunk base
    const int sg = 256 * h + 32 * wv + (lane & 31);   // this lane's state (mirrored halves)
    const int woff = (8 * h + wv) * 1024 + lane * 16; // fragment offset within a chunk

    unsigned int* flagW = flags + (size_t)(b * 2 + h) * 16;
    unsigned int* flagR = flags + (size_t)(b * 2 + (1 - h)) * 16;
    char* mboxW = mbox + (size_t)(b * 2 + h) * 1024;
    const char* mboxR = mbox + (size_t)(b * 2 + (1 - h)) * 1024;

    // ---- one-time preloads ----
    if (tid <= TT) {
        obs_l[tid] = obs[tid * BB + b];
        rew_l[tid] = rewards[tid * BB + b];
        done_l[tid] = dones[tid * BB + b];
        if (tid < TT) act_l[tid] = actions[tid * BB + b];
    }
    // transposed log-softmax policy row for state sg -> 16 registers
    float la16[16];
    {
        const float4* pr4 = (const float4*)(policy_logits + (size_t)sg * AA);
        float4 v0 = pr4[0], v1 = pr4[1], v2 = pr4[2], v3 = pr4[3];
        la16[0] = v0.x; la16[1] = v0.y; la16[2] = v0.z; la16[3] = v0.w;
        la16[4] = v1.x; la16[5] = v1.y; la16[6] = v1.z; la16[7] = v1.w;
        la16[8] = v2.x; la16[9] = v2.y; la16[10] = v2.z; la16[11] = v2.w;
        la16[12] = v3.x; la16[13] = v3.y; la16[14] = v3.z; la16[15] = v3.w;
        float mx = la16[0];
#pragma unroll
        for (int i = 1; i < 16; ++i) mx = fmaxf(mx, la16[i]);
        float sm = 0.f;
#pragma unroll
        for (int i = 0; i < 16; ++i) sm += __expf(la16[i] - mx);
        float ls = mx + __logf(sm);
#pragma unroll
        for (int i = 0; i < 16; ++i) la16[i] -= ls;
    }
    const float rm = r_mu[sg];
    const float rls = r_logsig[sg];
    const float inv_sig = __expf(-rls);
    const float reg = regime[b];

    // prior log-softmax with tid = global-state mapping (full 512 states in
    // this block's 512 threads), then redistribute via LDS to the sg mapping.
    {
        float px = prior_logits[tid];
        float wm0 = bflyMax(px);
        if (lane == 0) wrm[wv] = wm0;
        lds_barrier();
        float pm = wrm[0];
#pragma unroll
        for (int i = 1; i < 8; ++i) pm = fmaxf(pm, wrm[i]);
        float ws0 = bflySum(__expf(px - pm));
        if (lane == 0) wrs[wv] = ws0;
        lds_barrier();
        float psum = wrs[0];
#pragma unroll
        for (int i = 1; i < 8; ++i) psum += wrs[i];
        plds[tid] = px - pm - __logf(psum);
    }
    lds_barrier();
    float base_reg = plds[sg];

    // ---- prologue: fragments for t=0 (own + partner chunk halves) ----
    ulonglong2 fO[8], fP[8], gO[8], gP[8];
    {
        const int a0 = __builtin_amdgcn_readfirstlane(act_l[0]);
        const unsigned char* P0 = PB + (size_t)a0 * (16 * 16384) + woff;
#pragma unroll
        for (int c = 0; c < 8; ++c) {
            fO[c] = *(const ulonglong2*)(P0 + (size_t)(KOWN + c) * 16384);
            fP[c] = *(const ulonglong2*)(P0 + (size_t)(KOTH + c) * 16384);
        }
    }
    float obsv = obsT[(size_t)obs_l[0] * SS + sg];

    float log_prob = 0.f;
    float was_done = 0.f;

#define OWNC(c, CO, NO)                                                         \
    {                                                                           \
        long af = *(const long long*)(p8 + quad * 144 + (KOWN + (c)) * 8);      \
        accO0 = __builtin_amdgcn_mfma_f32_16x16x32_fp8_fp8((long)CO[(c)].x, af, accO0, 0, 0, 0); \
        accO1 = __builtin_amdgcn_mfma_f32_16x16x32_fp8_fp8((long)CO[(c)].y, af, accO1, 0, 0, 0); \
        NO[(c)] = *(const ulonglong2*)(Pn_ + (size_t)(KOWN + (c)) * 16384);     \
    }
#define OTHC(c, CP, NP)                                                         \
    {                                                                           \
        long af = *(const long long*)(p8 + quad * 144 + (KOTH + (c)) * 8);      \
        accP0 = __builtin_amdgcn_mfma_f32_16x16x32_fp8_fp8((long)CP[(c)].x, af, accP0, 0, 0, 0); \
        accP1 = __builtin_amdgcn_mfma_f32_16x16x32_fp8_fp8((long)CP[(c)].y, af, accP1, 0, 0, 0); \
        NP[(c)] = *(const ulonglong2*)(Pn_ + (size_t)(KOTH + (c)) * 16384);     \
    }

#define STEP(T, CO, CP, NO, NP)                                                 \
    {                                                                           \
        const int t_ = (T);                                                     \
        const float r_ = rew_l[t_];                                             \
        const int a_ = __builtin_amdgcn_readfirstlane(act_l[t_]);               \
        const float d_ = done_l[t_];                                            \
        const float done_ = fmaxf(was_done, d_);                                \
        const int tn_ = (t_ + 1 < TT) ? t_ + 1 : 0;                             \
        const int an_ = __builtin_amdgcn_readfirstlane(act_l[tn_]);             \
        const unsigned char* Pn_ = PB + (size_t)an_ * (16 * 16384) + woff;      \
        char* pw_ = mboxW + (t_ & 1) * 512;                                     \
        const char* pr_ = mboxR + (t_ & 1) * 512;                               \
        float obsv_next_ = obsT[(size_t)obs_l[t_ + 1] * SS + sg];               \
        /* ---- phase A ---- */                                                 \
        float diff_ = (r_ - rm) * inv_sig;                                      \
        float emis_ = obsv - 0.5f * diff_ * diff_ - rls - 0.5f * LOG2PI;        \
        float la_ = la16[0];                                                    \
        _Pragma("unroll")                                                       \
        for (int i = 1; i < 16; ++i) la_ = (a_ == i) ? la16[i] : la_;           \
        if (done_ == 1.0f || reg == 1.0f) la_ = 0.f;                            \
        float lq_ = base_reg + emis_ + la_;                                     \
        float wmax_ = halfMax(lq_);                                             \
        if (lane == 0) wrm[wv] = wmax_;                                         \
        lds_barrier(); /* B1 */                                                 \
        float mA_ = wrm[0];                                                     \
        _Pragma("unroll")                                                       \
        for (int i = 1; i < 8; ++i) mA_ = fmaxf(mA_, wrm[i]);                   \
        float exv_ = __expf(lq_ - mA_);                                         \
        if (lane < 32)                                                          \
            p8[(lane >> 3) * 144 + (KOWN + wv) * 8 + (lane & 7)] =              \
                (unsigned char)f32_to_e4m3(exv_ * 16.0f);                       \
        float wsum_ = halfSum(exv_);                                            \
        if (lane == 0) wrs[wv] = wsum_;                                         \
        lds_barrier(); /* B2: own p8 half + wrs published */                    \
        float sumA_ = wrs[0];                                                   \
        _Pragma("unroll")                                                       \
        for (int i = 1; i < 8; ++i) sumA_ += wrs[i];                            \
        /* ---- exchange ---- */                                                \
        if (wv == 6) { /* publisher */                                          \
            if (lane < 32) {                                                    \
                unsigned long long v_ = *(const unsigned long long*)(           \
                    p8 + (lane >> 3) * 144 + (KOWN + (lane & 7)) * 8);          \
                __hip_atomic_store((unsigned long long*)(pw_ + lane * 8), v_,   \
                                   __ATOMIC_RELAXED, __HIP_MEMORY_SCOPE_AGENT); \
            } else if (lane == 32) {                                            \
                __hip_atomic_store((unsigned int*)(pw_ + 256),                  \
                                   __float_as_uint(mA_),                        \
                                   __ATOMIC_RELAXED, __HIP_MEMORY_SCOPE_AGENT); \
            } else if (lane == 33) {                                            \
                __hip_atomic_store((unsigned int*)(pw_ + 260),                  \
                                   __float_as_uint(sumA_),                      \
                                   __ATOMIC_RELAXED, __HIP_MEMORY_SCOPE_AGENT); \
            }                                                                   \
            if (lane == 0)                                                      \
                __hip_atomic_store(flagW, (unsigned)(t_ + 1),                   \
                                   __ATOMIC_RELEASE, __HIP_MEMORY_SCOPE_AGENT); \
        }                                                                       \
        if (wv == 7) { /* receiver */                                           \
            while (__hip_atomic_load(flagR, __ATOMIC_ACQUIRE,                   \
                                     __HIP_MEMORY_SCOPE_AGENT) <                \
                   (unsigned)(t_ + 1))                                          \
                __builtin_amdgcn_s_sleep(1);                                    \
            if (lane < 32) {                                                    \
                unsigned long long v_ = __hip_atomic_load(                      \
                    (const unsigned long long*)(pr_ + lane * 8),                \
                    __ATOMIC_RELAXED, __HIP_MEMORY_SCOPE_AGENT);                \
                *(unsigned long long*)(p8 + (lane >> 3) * 144 +                 \
                                       (KOTH + (lane & 7)) * 8) = v_;           \
            } else if (lane == 32) {                                            \
                xsc[0] = __uint_as_float(__hip_atomic_load(                     \
                    (const unsigned int*)(pr_ + 256),                           \
                    __ATOMIC_RELAXED, __HIP_MEMORY_SCOPE_AGENT));               \
            } else if (lane == 33) {                                            \
                xsc[1] = __uint_as_float(__hip_atomic_load(                     \
                    (const unsigned int*)(pr_ + 260),                           \
                    __ATOMIC_RELAXED, __HIP_MEMORY_SCOPE_AGENT));               \
            }                                                                   \
        }                                                                       \
        /* ---- phase B: own-half MFMAs overlap the exchange ---- */            \
        f32x4 accO0 = {0.f, 0.f, 0.f, 0.f};                                     \
        f32x4 accO1 = {0.f, 0.f, 0.f, 0.f};                                     \
        f32x4 accP0 = {0.f, 0.f, 0.f, 0.f};                                     \
        f32x4 accP1 = {0.f, 0.f, 0.f, 0.f};                                     \
        OWNC(0, CO, NO) OWNC(1, CO, NO) OWNC(2, CO, NO) OWNC(3, CO, NO)         \
        OWNC(4, CO, NO) OWNC(5, CO, NO) OWNC(6, CO, NO) OWNC(7, CO, NO)         \
        lds_barrier(); /* B3: partner p8 half + xsc published */                \
        float mB_ = xsc[0];                                                     \
        float sumB_ = xsc[1];                                                   \
        OTHC(0, CP, NP) OTHC(1, CP, NP) OTHC(2, CP, NP) OTHC(3, CP, NP)         \
        OTHC(4, CP, NP) OTHC(5, CP, NP) OTHC(6, CP, NP) OTHC(7, CP, NP)         \
        float m_ = fmaxf(mA_, mB_);                                             \
        float sO_ = __expf(mA_ - m_);                                           \
        float sP_ = __expf(mB_ - m_);                                           \
        float sum_ = sO_ * sumA_ + sP_ * sumB_;                                 \
        float lse_ = m_ + __logf(sum_);                                         \
        float lqo_ = lse_ * (1.0f - was_done);                                  \
        if (!isinf(log_prob)) log_prob += lqo_;                                 \
        was_done = done_;                                                       \
        float av0_ = sO_ * accO0[0] + sP_ * accP0[0];                           \
        float av1_ = sO_ * accO1[0] + sP_ * accP1[0];                           \
        float g0_ = __shfl(av0_, lane & 15);                                    \
        float g1_ = __shfl(av1_, lane & 15);                                    \
        float av_ = ((lane & 31) < 16) ? g0_ : g1_;                             \
        base_reg = m_ - lqo_ - LOG4096 + __logf(av_);                           \
        obsv = obsv_next_;                                                      \
        asm volatile("" ::: "memory"); /* pin next-step loads inside step */    \
    }

    for (int t = 0; t < TT; t += 2) {
        STEP(t, fO, fP, gO, gP)
        STEP(t + 1, gO, gP, fO, fP)
    }
#undef STEP
#undef OWNC
#undef OTHC

    // final step t = TT (no action term, no transition; scalars-only exchange)
    {
        const float r = rew_l[TT];
        float diff = (r - rm) * inv_sig;
        float emis = obsv - 0.5f * diff * diff - rls - 0.5f * LOG2PI;
        float lq = base_reg + emis;
        float wmax = halfMax(lq);
        if (lane == 0) wrm[wv] = wmax;
        lds_barrier();
        float mA = wrm[0];
#pragma unroll
        for (int i = 1; i < 8; ++i) mA = fmaxf(mA, wrm[i]);
        float wsum = halfSum(__expf(lq - mA));
        if (lane == 0) wrs[wv] = wsum;
        lds_barrier();
        float sumA = wrs[0];
#pragma unroll
        for (int i = 1; i < 8; ++i) sumA += wrs[i];
        char* pw_ = mboxW + (TT & 1) * 512;
        const char* pr_ = mboxR + (TT & 1) * 512;
        if (wv == 6) {
            if (lane == 32)
                __hip_atomic_store((unsigned int*)(pw_ + 256), __float_as_uint(mA),
                                   __ATOMIC_RELAXED, __HIP_MEMORY_SCOPE_AGENT);
            else if (lane == 33)
                __hip_atomic_store((unsigned int*)(pw_ + 260), __float_as_uint(sumA),
                                   __ATOMIC_RELAXED, __HIP_MEMORY_SCOPE_AGENT);
            if (lane == 0)
                __hip_atomic_store(flagW, (unsigned)(TT + 1),
                                   __ATOMIC_RELEASE, __HIP_MEMORY_SCOPE_AGENT);
        }
        if (wv == 7) {
            while (__hip_atomic_load(flagR, __ATOMIC_ACQUIRE,
                                     __HIP_MEMORY_SCOPE_AGENT) < (unsigned)(TT + 1))
                __builtin_amdgcn_s_sleep(1);
            if (lane == 32)
                xsc[0] = __uint_as_float(__hip_atomic_load(
                    (const unsigned int*)(pr_ + 256),
                    __ATOMIC_RELAXED, __HIP_MEMORY_SCOPE_AGENT));
            else if (lane == 33)
                xsc[1] = __uint_as_float(__hip_atomic_load(
                    (const unsigned int*)(pr_ + 260),
                    __ATOMIC_RELAXED, __HIP_MEMORY_SCOPE_AGENT));
        }
        lds_barrier();
        float mB = xsc[0], sumB = xsc[1];
        float m = fmaxf(mA, mB);
        float sum = __expf(mA - m) * sumA + __expf(mB - m) * sumB;
        float lse = m + __logf(sum);
        float lq_ord = lse * (1.0f - was_done);
        if (!isinf(log_prob)) log_prob += lq_ord;
    }

    if (h == 0 && tid == 0) out[b] = log_prob;
}

// ---------------- launch ----------------
extern "C" void kernel_launch(void* const* d_in, const int* in_sizes, int n_in,
                              void* d_out, int out_size, void* d_ws, size_t ws_size,
                              hipStream_t stream) {
    const float* regime = (const float*)d_in[0];
    const int* obs = (const int*)d_in[1];
    const float* rewards = (const float*)d_in[2];
    const float* dones = (const float*)d_in[3];
    const int* actions = (const int*)d_in[4];
    const float* prior_logits = (const float*)d_in[5];
    const float* trans_logits = (const float*)d_in[6];
    const float* obs_logits = (const float*)d_in[7];
    const float* policy_logits = (const float*)d_in[8];
    const float* r_mu = (const float*)d_in[9];
    const float* r_logsig = (const float*)d_in[10];
    float* out = (float*)d_out;

    char* ws = (char*)d_ws;
    unsigned char* PB = (unsigned char*)ws;                    // A*S*S fp8 = 4 MB
    float* obsT = (float*)(ws + (size_t)AA * SS * SS);         // O*S fp32 = 8 MB
    size_t tail = (size_t)AA * SS * SS + (size_t)OO * SS * 4;  // 12 MB
    float* mo = (float*)(ws + tail);                           // S
    float* lo = mo + SS;                                       // S
    unsigned int* flags = (unsigned int*)(ws + tail + 16384);  // 128 x 64 B = 8 KB
    char* mbox = (char*)(ws + tail + 16384 + 8192);            // 128 x 1 KB = 128 KB

    hipMemsetAsync(flags, 0, 128 * 64, stream);
    k_pack<<<256, 1024, 0, stream>>>(trans_logits, PB);
    k_obs_stats<<<SS, 256, 0, stream>>>(obs_logits, mo, lo);
    k_obsT<<<(OO / 64) * (SS / 64), 256, 0, stream>>>(obs_logits, mo, lo, obsT);
    k_main<<<2 * BB, 512, 0, stream>>>(regime, obs, rewards, dones, actions,
                                       prior_logits, PB, obsT, policy_logits,
                                       r_mu, r_logsig, flags, mbox, out);
}

// Round 4
// 513.879 us; speedup vs baseline: 1.6766x; 1.6766x over previous
//
#include <hip/hip_runtime.h>
#include <math.h>

#define DI __device__ __forceinline__

constexpr int BB = 64;     // batch
constexpr int TT = 128;    // action steps (obs/rewards have TT+1)
constexpr int SS = 512;    // states
constexpr int AA = 16;     // actions
constexpr int OO = 4096;   // observations
constexpr float LOG2PI = 1.8378770664093453f;
constexpr float LOG4096 = 8.317766166719343f;  // log(16*256)

typedef float f32x4 __attribute__((ext_vector_type(4)));

// LDS-only barrier: drains LDS ops then barriers (does NOT drain vmcnt,
// so in-flight global fragment loads survive across it).
DI void lds_barrier() {
    asm volatile("s_waitcnt lgkmcnt(0)\n\ts_barrier" ::: "memory");
}

// ---------------- fp8 e4m3fn converter (RTNE), x in [0, 448) ----------------
DI unsigned int f32_to_e4m3(float x) {
    unsigned int u = __float_as_uint(x);
    unsigned int lsb = (u >> 20) & 1u;
    unsigned int rounded = u + 0x7ffffu + lsb;          // RTNE into 3-bit mantissa
    int e8 = (int)(rounded >> 23) - 120;                // 127 - 7
    unsigned int m3 = (rounded >> 20) & 7u;
    unsigned int norm = ((unsigned int)e8 << 3) | m3;
    int sub = __float2int_rn(x * 512.0f);               // subnormal: multiples of 2^-9
    return (e8 <= 0) ? (unsigned int)sub : norm;
}

// ---------------- reduction helpers (wave64) ----------------
DI float bflyMax(float v) {
#pragma unroll
    for (int off = 32; off; off >>= 1) v = fmaxf(v, __shfl_xor(v, off));
    return v;
}
DI float bflySum(float v) {
#pragma unroll
    for (int off = 32; off; off >>= 1) v += __shfl_xor(v, off);
    return v;
}
DI float halfMax(float v) {
#pragma unroll
    for (int off = 16; off; off >>= 1) v = fmaxf(v, __shfl_xor(v, off));
    return v;
}
DI float halfSum(float v) {
#pragma unroll
    for (int off = 16; off; off >>= 1) v += __shfl_xor(v, off);
    return v;
}

template <int NW>
DI float blockMax(float v, float* wr) {
    v = bflyMax(v);
    const int lane = threadIdx.x & 63, wv = threadIdx.x >> 6;
    if (lane == 0) wr[wv] = v;
    __syncthreads();
    float r = wr[0];
#pragma unroll
    for (int i = 1; i < NW; ++i) r = fmaxf(r, wr[i]);
    __syncthreads();
    return r;
}
template <int NW>
DI float blockSum(float v, float* wr) {
    v = bflySum(v);
    const int lane = threadIdx.x & 63, wv = threadIdx.x >> 6;
    if (lane == 0) wr[wv] = v;
    __syncthreads();
    float r = wr[0];
#pragma unroll
    for (int i = 1; i < NW; ++i) r += wr[i];
    __syncthreads();
    return r;
}

// ---------------- precompute kernels ----------------

// Fused softmax + fp8 quantize (x256) + MFMA-B-fragment swizzle (R3 layout).
// PB byte addr = (a*16 + kt)*16384 + ntp*1024 + lane*16 + (nt&1)*8 + j
// fragment byte j of (kt, nt, lane) = P[a][kt*32 + (lane>>4)*8 + j][nt*16 + (lane&15)]*256
__global__ __launch_bounds__(1024) void k_pack(const float* __restrict__ tl,
                                               unsigned char* __restrict__ PB) {
    __shared__ unsigned char lds[16384];
    const int a = blockIdx.x >> 4;
    const int kt = blockIdx.x & 15;
    const int tid = threadIdx.x;
    const int r = tid >> 5;       // 0..31
    const int nt = tid & 31;      // 0..31
    const int k = kt * 32 + r;
    const float* row = tl + ((size_t)a * SS + k) * SS + nt * 16;

    float x[16];
#pragma unroll
    for (int i = 0; i < 4; ++i) {
        float4 v = ((const float4*)row)[i];
        x[4 * i] = v.x; x[4 * i + 1] = v.y; x[4 * i + 2] = v.z; x[4 * i + 3] = v.w;
    }
    float mx = -INFINITY;
#pragma unroll
    for (int i = 0; i < 16; ++i) mx = fmaxf(mx, x[i]);
    mx = halfMax(mx);   // row lives in one 32-lane half
    float e[16];
    float sm = 0.f;
#pragma unroll
    for (int i = 0; i < 16; ++i) { e[i] = __expf(x[i] - mx); sm += e[i]; }
    sm = halfSum(sm);
    const float scale = 256.0f / sm;

    const int base = (nt >> 1) * 1024 + ((r >> 3) * 16) * 16 + (nt & 1) * 8 + (r & 7);
#pragma unroll
    for (int i = 0; i < 16; ++i) {
        lds[base + i * 16] = (unsigned char)f32_to_e4m3(e[i] * scale);
    }
    __syncthreads();

    ulonglong2* dst = (ulonglong2*)(PB + (size_t)(a * 16 + kt) * 16384);
    dst[tid] = ((const ulonglong2*)lds)[tid];
}

__global__ __launch_bounds__(256) void k_obs_stats(const float* __restrict__ ol,
                                                   float* __restrict__ mo,
                                                   float* __restrict__ lo) {
    __shared__ float wr[4];
    const int s = blockIdx.x;
    const float* in = ol + (size_t)s * OO;
    const int tid = threadIdx.x;
    float mx = -INFINITY;
    for (int i = tid; i < OO; i += 256) mx = fmaxf(mx, in[i]);
    float m = blockMax<4>(mx, wr);
    float sm = 0.f;
    for (int i = tid; i < OO; i += 256) sm += __expf(in[i] - m);
    float sum = blockSum<4>(sm, wr);
    if (tid == 0) { mo[s] = m; lo[s] = __logf(sum); }
}

__global__ __launch_bounds__(256) void k_obsT(const float* __restrict__ ol,
                                              const float* __restrict__ mo,
                                              const float* __restrict__ lo,
                                              float* __restrict__ obsT) {
    __shared__ float tile[64][65];
    const int tO = blockIdx.x % (OO / 64);
    const int tS = blockIdx.x / (OO / 64);
    const int o0 = tO * 64, s0 = tS * 64;
    const int cc = threadIdx.x & 63, rr = threadIdx.x >> 6;
#pragma unroll
    for (int j = 0; j < 16; ++j) {
        int r = rr + j * 4;
        tile[r][cc] = ol[(size_t)(s0 + r) * OO + o0 + cc] - mo[s0 + r] - lo[s0 + r];
    }
    __syncthreads();
#pragma unroll
    for (int j = 0; j < 16; ++j) {
        int r = rr + j * 4;
        obsT[(size_t)(o0 + r) * SS + s0 + cc] = tile[cc][r];
    }
}

// ---------------- main sequential-scan kernel ----------------
// one block per batch element, 512 threads = 8 waves, thread == state.
// Per step: ALL 16 chunks of the current action's panel are loaded in one
// burst at the top of the step (32 dwordx4 loads/wave -> 128 fragment VGPRs
// held live), pinned by sched_barrier(0) so LLVM cannot sink them to their
// uses. Phase A's softmax/barrier chain (~1000 cy) then runs entirely under
// the L2->CU stream, and phase B's chunk c waits on a load issued ~(1000 +
// 256*c) cy earlier -> near-zero exposed latency. This is the fix for R2's
// VGPR=84 symptom (compiler had sunk the loads just-in-time, exposing queued
// L2 latency in every CHUNK_H). lqprev handoff stays register-only via
// shuffles; 2 LDS-only barriers per step (vmcnt survives them).
__global__ __launch_bounds__(512, 2) void k_main(
    const float* __restrict__ regime, const int* __restrict__ obs,
    const float* __restrict__ rewards, const float* __restrict__ dones,
    const int* __restrict__ actions, const float* __restrict__ prior_logits,
    const unsigned char* __restrict__ PB, const float* __restrict__ obsT,
    const float* __restrict__ policy_logits, const float* __restrict__ r_mu,
    const float* __restrict__ r_logsig, float* __restrict__ out) {
    __shared__ float wrm[8], wrs[8];
    __shared__ alignas(16) unsigned char p8[4 * 144 + 16];  // [quad][16 kt x 8B], 144-pad
    __shared__ int obs_l[TT + 1];
    __shared__ float rew_l[TT + 1];
    __shared__ float done_l[TT + 1];
    __shared__ int act_l[TT];

    const int b = blockIdx.x;
    const int tid = threadIdx.x;
    const int wv = tid >> 6, lane = tid & 63, quad = lane >> 4;
    const int s = tid;
    const int wvl16 = wv * 2048 + lane * 16;   // fragment offset within a 16 KB chunk
    const int p8idx = ((s >> 3) & 3) * 144 + (s >> 5) * 8 + (s & 7);

    // ---- one-time preloads ----
    if (tid <= TT) {
        obs_l[tid] = obs[tid * BB + b];
        rew_l[tid] = rewards[tid * BB + b];
        done_l[tid] = dones[tid * BB + b];
        if (tid < TT) act_l[tid] = actions[tid * BB + b];
    }
    // transposed log-softmax policy -> 16 registers per thread
    float la16[16];
    {
        const float4* pr4 = (const float4*)(policy_logits + (size_t)s * AA);
        float4 v0 = pr4[0], v1 = pr4[1], v2 = pr4[2], v3 = pr4[3];
        la16[0] = v0.x; la16[1] = v0.y; la16[2] = v0.z; la16[3] = v0.w;
        la16[4] = v1.x; la16[5] = v1.y; la16[6] = v1.z; la16[7] = v1.w;
        la16[8] = v2.x; la16[9] = v2.y; la16[10] = v2.z; la16[11] = v2.w;
        la16[12] = v3.x; la16[13] = v3.y; la16[14] = v3.z; la16[15] = v3.w;
        float mx = la16[0];
#pragma unroll
        for (int i = 1; i < 16; ++i) mx = fmaxf(mx, la16[i]);
        float sm = 0.f;
#pragma unroll
        for (int i = 0; i < 16; ++i) sm += __expf(la16[i] - mx);
        float ls = mx + __logf(sm);
#pragma unroll
        for (int i = 0; i < 16; ++i) la16[i] -= ls;
    }
    const float rm = r_mu[s];
    const float rls = r_logsig[s];
    const float inv_sig = __expf(-rls);
    const float reg = regime[b];

    // inline prior log-softmax (its barriers also publish the preloads)
    float px = prior_logits[s];
    {
        float wm0 = bflyMax(px);
        if (lane == 0) wrm[wv] = wm0;
    }
    lds_barrier();
    float pm = wrm[0];
#pragma unroll
    for (int i = 1; i < 8; ++i) pm = fmaxf(pm, wrm[i]);
    {
        float ws0 = bflySum(__expf(px - pm));
        if (lane == 0) wrs[wv] = ws0;
    }
    lds_barrier();
    float psum = wrs[0];
#pragma unroll
    for (int i = 1; i < 8; ++i) psum += wrs[i];
    float base_reg = px - pm - __logf(psum);   // prior_reg; loop-carried in reg

    float obsv = obsT[(size_t)obs_l[0] * SS + s];

    float log_prob = 0.f;
    float was_done = 0.f;

    for (int t = 0; t < TT; ++t) {
        const float r = rew_l[t];
        const int a = __builtin_amdgcn_readfirstlane(act_l[t]);
        const float d = done_l[t];
        const float done = fmaxf(was_done, d);
        const unsigned char* Pw = PB + (size_t)a * (16 * 16384) + wvl16;

        // ---- burst-issue the whole step's panel slice (32 loads/wave) ----
        ulonglong2 fA[16], fB[16];
#pragma unroll
        for (int c = 0; c < 16; ++c) {
            fA[c] = *(const ulonglong2*)(Pw + (size_t)c * 16384);
            fB[c] = *(const ulonglong2*)(Pw + (size_t)c * 16384 + 1024);
        }
        float obsv_next = obsT[(size_t)obs_l[t + 1] * SS + s];
        __builtin_amdgcn_sched_barrier(0);   // pin: no instruction crosses

        // ---- phase A: emission + action term + block softmax ----
        float diff = (r - rm) * inv_sig;
        float emis = obsv - 0.5f * diff * diff - rls - 0.5f * LOG2PI;
        float la = la16[0];
#pragma unroll
        for (int i = 1; i < 16; ++i) la = (a == i) ? la16[i] : la;
        if (done == 1.0f || reg == 1.0f) la = 0.f;
        float lq = base_reg + emis + la;

        float wmax = bflyMax(lq);
        if (lane == 0) wrm[wv] = wmax;
        lds_barrier();  // B1
        float m = wrm[0];
#pragma unroll
        for (int i = 1; i < 8; ++i) m = fmaxf(m, wrm[i]);

        float exv = __expf(lq - m);
        p8[p8idx] = (unsigned char)f32_to_e4m3(exv * 16.0f);
        float wsum = bflySum(exv);
        if (lane == 0) wrs[wv] = wsum;
        lds_barrier();  // B2 (publishes p8)
        float sum = wrs[0];
#pragma unroll
        for (int i = 1; i < 8; ++i) sum += wrs[i];
        float lse = m + __logf(sum);
        float lq_orda = lse * (1.0f - was_done);
        if (!isinf(log_prob)) log_prob += lq_orda;
        was_done = done;

        // ---- phase B: 16 ktiles, MFMA from the burst registers ----
        const float basev = m - lq_orda - LOG4096;
        f32x4 acc0 = {0.f, 0.f, 0.f, 0.f};
        f32x4 acc1 = {0.f, 0.f, 0.f, 0.f};
        f32x4 acc2 = {0.f, 0.f, 0.f, 0.f};
        f32x4 acc3 = {0.f, 0.f, 0.f, 0.f};

#define CHUNK(c)                                                                \
        {                                                                       \
            long af = *(const long long*)(p8 + quad * 144 + (c) * 8);           \
            acc0 = __builtin_amdgcn_mfma_f32_16x16x32_fp8_fp8((long)fA[(c)].x, af, acc0, 0, 0, 0); \
            acc1 = __builtin_amdgcn_mfma_f32_16x16x32_fp8_fp8((long)fA[(c)].y, af, acc1, 0, 0, 0); \
            acc2 = __builtin_amdgcn_mfma_f32_16x16x32_fp8_fp8((long)fB[(c)].x, af, acc2, 0, 0, 0); \
            acc3 = __builtin_amdgcn_mfma_f32_16x16x32_fp8_fp8((long)fB[(c)].y, af, acc3, 0, 0, 0); \
        }
        CHUNK(0)  CHUNK(1)  CHUNK(2)  CHUNK(3)
        CHUNK(4)  CHUNK(5)  CHUNK(6)  CHUNK(7)
        CHUNK(8)  CHUNK(9)  CHUNK(10) CHUNK(11)
        CHUNK(12) CHUNK(13) CHUNK(14) CHUNK(15)
#undef CHUNK

        // ---- register-only handoff: state wv*64+16q+l = acc_q[0] @ lane l ----
        float t0 = __shfl(acc0[0], lane & 15);
        float t1 = __shfl(acc1[0], lane & 15);
        float t2 = __shfl(acc2[0], lane & 15);
        float t3 = __shfl(acc3[0], lane & 15);
        float av = quad == 0 ? t0 : (quad == 1 ? t1 : (quad == 2 ? t2 : t3));
        base_reg = basev + __logf(av);
        obsv = obsv_next;
    }

    // final step t = TT (no action term, no transition)
    {
        const float r = rew_l[TT];
        float diff = (r - rm) * inv_sig;
        float emis = obsv - 0.5f * diff * diff - rls - 0.5f * LOG2PI;
        float lq = base_reg + emis;
        float wmax = bflyMax(lq);
        if (lane == 0) wrm[wv] = wmax;
        lds_barrier();
        float m = wrm[0];
#pragma unroll
        for (int i = 1; i < 8; ++i) m = fmaxf(m, wrm[i]);
        float wsum = bflySum(__expf(lq - m));
        if (lane == 0) wrs[wv] = wsum;
        lds_barrier();
        float sum = wrs[0];
#pragma unroll
        for (int i = 1; i < 8; ++i) sum += wrs[i];
        float lse = m + __logf(sum);
        float lq_ord = lse * (1.0f - was_done);
        if (!isinf(log_prob)) log_prob += lq_ord;
    }

    if (tid == 0) out[b] = log_prob;
}

// ---------------- launch ----------------
extern "C" void kernel_launch(void* const* d_in, const int* in_sizes, int n_in,
                              void* d_out, int out_size, void* d_ws, size_t ws_size,
                              hipStream_t stream) {
    const float* regime = (const float*)d_in[0];
    const int* obs = (const int*)d_in[1];
    const float* rewards = (const float*)d_in[2];
    const float* dones = (const float*)d_in[3];
    const int* actions = (const int*)d_in[4];
    const float* prior_logits = (const float*)d_in[5];
    const float* trans_logits = (const float*)d_in[6];
    const float* obs_logits = (const float*)d_in[7];
    const float* policy_logits = (const float*)d_in[8];
    const float* r_mu = (const float*)d_in[9];
    const float* r_logsig = (const float*)d_in[10];
    float* out = (float*)d_out;

    char* ws = (char*)d_ws;
    unsigned char* PB = (unsigned char*)ws;                    // A*S*S fp8 = 4 MB
    float* obsT = (float*)(ws + (size_t)AA * SS * SS);         // O*S fp32 = 8 MB
    float* mo = (float*)(ws + (size_t)AA * SS * SS + (size_t)OO * SS * 4);  // S
    float* lo = mo + SS;                                       // S

    k_pack<<<256, 1024, 0, stream>>>(trans_logits, PB);
    k_obs_stats<<<SS, 256, 0, stream>>>(obs_logits, mo, lo);
    k_obsT<<<(OO / 64) * (SS / 64), 256, 0, stream>>>(obs_logits, mo, lo, obsT);
    k_main<<<BB, 512, 0, stream>>>(regime, obs, rewards, dones, actions, prior_logits,
                                   PB, obsT, policy_logits, r_mu, r_logsig, out);
}

// Round 5
// 501.480 us; speedup vs baseline: 1.7181x; 1.0247x over previous
//
#include <hip/hip_runtime.h>
#include <math.h>

#define DI __device__ __forceinline__

constexpr int BB = 64;     // batch
constexpr int TT = 128;    // action steps (obs/rewards have TT+1)
constexpr int SS = 512;    // states
constexpr int AA = 16;     // actions
constexpr int OO = 4096;   // observations
constexpr float LOG2PI = 1.8378770664093453f;
constexpr float LOG4096 = 8.317766166719343f;  // log(16*256)

typedef float f32x4 __attribute__((ext_vector_type(4)));
typedef long long ll2 __attribute__((ext_vector_type(2)));

// LDS-only barrier: drains LDS ops then barriers (does NOT drain vmcnt,
// so in-flight global fragment loads survive across it).
DI void lds_barrier() {
    asm volatile("s_waitcnt lgkmcnt(0)\n\ts_barrier" ::: "memory");
}

// ---------------- fp8 e4m3fn converter (RTNE), x in [0, 448) ----------------
DI unsigned int f32_to_e4m3(float x) {
    unsigned int u = __float_as_uint(x);
    unsigned int lsb = (u >> 20) & 1u;
    unsigned int rounded = u + 0x7ffffu + lsb;          // RTNE into 3-bit mantissa
    int e8 = (int)(rounded >> 23) - 120;                // 127 - 7
    unsigned int m3 = (rounded >> 20) & 7u;
    unsigned int norm = ((unsigned int)e8 << 3) | m3;
    int sub = __float2int_rn(x * 512.0f);               // subnormal: multiples of 2^-9
    return (e8 <= 0) ? (unsigned int)sub : norm;
}

// ---------------- reduction helpers (wave64) ----------------
DI float bflyMax(float v) {
#pragma unroll
    for (int off = 32; off; off >>= 1) v = fmaxf(v, __shfl_xor(v, off));
    return v;
}
DI float bflySum(float v) {
#pragma unroll
    for (int off = 32; off; off >>= 1) v += __shfl_xor(v, off);
    return v;
}
DI float halfMax(float v) {
#pragma unroll
    for (int off = 16; off; off >>= 1) v = fmaxf(v, __shfl_xor(v, off));
    return v;
}
DI float halfSum(float v) {
#pragma unroll
    for (int off = 16; off; off >>= 1) v += __shfl_xor(v, off);
    return v;
}

template <int NW>
DI float blockMax(float v, float* wr) {
    v = bflyMax(v);
    const int lane = threadIdx.x & 63, wv = threadIdx.x >> 6;
    if (lane == 0) wr[wv] = v;
    __syncthreads();
    float r = wr[0];
#pragma unroll
    for (int i = 1; i < NW; ++i) r = fmaxf(r, wr[i]);
    __syncthreads();
    return r;
}
template <int NW>
DI float blockSum(float v, float* wr) {
    v = bflySum(v);
    const int lane = threadIdx.x & 63, wv = threadIdx.x >> 6;
    if (lane == 0) wr[wv] = v;
    __syncthreads();
    float r = wr[0];
#pragma unroll
    for (int i = 1; i < NW; ++i) r += wr[i];
    __syncthreads();
    return r;
}

// ---------------- precompute kernels ----------------

// Fused softmax + fp8 quantize (x256) + MFMA-B-fragment swizzle (R3 layout).
// PB byte addr = (a*16 + kt)*16384 + ntp*1024 + lane*16 + (nt&1)*8 + j
// fragment byte j of (kt, nt, lane) = P[a][kt*32 + (lane>>4)*8 + j][nt*16 + (lane&15)]*256
__global__ __launch_bounds__(1024) void k_pack(const float* __restrict__ tl,
                                               unsigned char* __restrict__ PB) {
    __shared__ unsigned char lds[16384];
    const int a = blockIdx.x >> 4;
    const int kt = blockIdx.x & 15;
    const int tid = threadIdx.x;
    const int r = tid >> 5;       // 0..31
    const int nt = tid & 31;      // 0..31
    const int k = kt * 32 + r;
    const float* row = tl + ((size_t)a * SS + k) * SS + nt * 16;

    float x[16];
#pragma unroll
    for (int i = 0; i < 4; ++i) {
        float4 v = ((const float4*)row)[i];
        x[4 * i] = v.x; x[4 * i + 1] = v.y; x[4 * i + 2] = v.z; x[4 * i + 3] = v.w;
    }
    float mx = -INFINITY;
#pragma unroll
    for (int i = 0; i < 16; ++i) mx = fmaxf(mx, x[i]);
    mx = halfMax(mx);   // row lives in one 32-lane half
    float e[16];
    float sm = 0.f;
#pragma unroll
    for (int i = 0; i < 16; ++i) { e[i] = __expf(x[i] - mx); sm += e[i]; }
    sm = halfSum(sm);
    const float scale = 256.0f / sm;

    const int base = (nt >> 1) * 1024 + ((r >> 3) * 16) * 16 + (nt & 1) * 8 + (r & 7);
#pragma unroll
    for (int i = 0; i < 16; ++i) {
        lds[base + i * 16] = (unsigned char)f32_to_e4m3(e[i] * scale);
    }
    __syncthreads();

    ulonglong2* dst = (ulonglong2*)(PB + (size_t)(a * 16 + kt) * 16384);
    dst[tid] = ((const ulonglong2*)lds)[tid];
}

__global__ __launch_bounds__(256) void k_obs_stats(const float* __restrict__ ol,
                                                   float* __restrict__ mo,
                                                   float* __restrict__ lo) {
    __shared__ float wr[4];
    const int s = blockIdx.x;
    const float* in = ol + (size_t)s * OO;
    const int tid = threadIdx.x;
    float mx = -INFINITY;
    for (int i = tid; i < OO; i += 256) mx = fmaxf(mx, in[i]);
    float m = blockMax<4>(mx, wr);
    float sm = 0.f;
    for (int i = tid; i < OO; i += 256) sm += __expf(in[i] - m);
    float sum = blockSum<4>(sm, wr);
    if (tid == 0) { mo[s] = m; lo[s] = __logf(sum); }
}

__global__ __launch_bounds__(256) void k_obsT(const float* __restrict__ ol,
                                              const float* __restrict__ mo,
                                              const float* __restrict__ lo,
                                              float* __restrict__ obsT) {
    __shared__ float tile[64][65];
    const int tO = blockIdx.x % (OO / 64);
    const int tS = blockIdx.x / (OO / 64);
    const int o0 = tO * 64, s0 = tS * 64;
    const int cc = threadIdx.x & 63, rr = threadIdx.x >> 6;
#pragma unroll
    for (int j = 0; j < 16; ++j) {
        int r = rr + j * 4;
        tile[r][cc] = ol[(size_t)(s0 + r) * OO + o0 + cc] - mo[s0 + r] - lo[s0 + r];
    }
    __syncthreads();
#pragma unroll
    for (int j = 0; j < 16; ++j) {
        int r = rr + j * 4;
        obsT[(size_t)(o0 + r) * SS + s0 + cc] = tile[cc][r];
    }
}

// ---------------- main sequential-scan kernel ----------------
// one block per batch element, 512 threads = 8 waves, thread == state.
// All 33 per-step vmem ops (obsv + 32 fragment dwordx4) are VOLATILE INLINE
// ASM with "=v" outputs: the scheduler cannot sink them, the allocator cannot
// serialize them (asm outputs aren't rematerializable), and SIInsertWaitcnts
// doesn't track them -> the loop contains ZERO compiler vmcnt waits. We own
// the wait schedule: descending literal s_waitcnt vmcnt(30-2c) before chunk
// c, each followed by sched_barrier(0) so MFMAs can't hoist past the wait
// (guide rule #18). Phase A's softmax/barrier chain runs entirely under the
// 33-load stream; the two LDS-only barriers don't drain vmcnt. Step scalars
// (a, r, done, obs-voffset) are prefetched one step ahead into registers so
// the burst issues with no LDS-latency lead-in.
__global__ __launch_bounds__(512, 2) void k_main(
    const float* __restrict__ regime, const int* __restrict__ obs,
    const float* __restrict__ rewards, const float* __restrict__ dones,
    const int* __restrict__ actions, const float* __restrict__ prior_logits,
    const unsigned char* __restrict__ PB, const float* __restrict__ obsT,
    const float* __restrict__ policy_logits, const float* __restrict__ r_mu,
    const float* __restrict__ r_logsig, float* __restrict__ out) {
    __shared__ float wrm[8], wrs[8];
    __shared__ alignas(16) unsigned char p8[4 * 144 + 16];  // [quad][16 kt x 8B], 144-pad
    __shared__ int obs_l[TT + 1];
    __shared__ float rew_l[TT + 1];
    __shared__ float done_l[TT + 1];
    __shared__ int act_l[TT];

    const int b = blockIdx.x;
    const int tid = threadIdx.x;
    const int wv = tid >> 6, lane = tid & 63, quad = lane >> 4;
    const int s = tid;
    const int wvl16 = wv * 2048 + lane * 16;   // fragment byte offset within a chunk
    const int p8idx = ((s >> 3) & 3) * 144 + (s >> 5) * 8 + (s & 7);

    // ---- one-time preloads ----
    if (tid <= TT) {
        obs_l[tid] = obs[tid * BB + b];
        rew_l[tid] = rewards[tid * BB + b];
        done_l[tid] = dones[tid * BB + b];
        if (tid < TT) act_l[tid] = actions[tid * BB + b];
    }
    // transposed log-softmax policy -> 16 registers per thread
    float la16[16];
    {
        const float4* pr4 = (const float4*)(policy_logits + (size_t)s * AA);
        float4 v0 = pr4[0], v1 = pr4[1], v2 = pr4[2], v3 = pr4[3];
        la16[0] = v0.x; la16[1] = v0.y; la16[2] = v0.z; la16[3] = v0.w;
        la16[4] = v1.x; la16[5] = v1.y; la16[6] = v1.z; la16[7] = v1.w;
        la16[8] = v2.x; la16[9] = v2.y; la16[10] = v2.z; la16[11] = v2.w;
        la16[12] = v3.x; la16[13] = v3.y; la16[14] = v3.z; la16[15] = v3.w;
        float mx = la16[0];
#pragma unroll
        for (int i = 1; i < 16; ++i) mx = fmaxf(mx, la16[i]);
        float sm = 0.f;
#pragma unroll
        for (int i = 0; i < 16; ++i) sm += __expf(la16[i] - mx);
        float ls = mx + __logf(sm);
#pragma unroll
        for (int i = 0; i < 16; ++i) la16[i] -= ls;
    }
    const float rm = r_mu[s];
    const float rls = r_logsig[s];
    const float inv_sig = __expf(-rls);
    const float reg = regime[b];

    // inline prior log-softmax (its barriers also publish the preloads)
    float px = prior_logits[s];
    {
        float wm0 = bflyMax(px);
        if (lane == 0) wrm[wv] = wm0;
    }
    lds_barrier();
    float pm = wrm[0];
#pragma unroll
    for (int i = 1; i < 8; ++i) pm = fmaxf(pm, wrm[i]);
    {
        float ws0 = bflySum(__expf(px - pm));
        if (lane == 0) wrs[wv] = ws0;
    }
    lds_barrier();
    float psum = wrs[0];
#pragma unroll
    for (int i = 1; i < 8; ++i) psum += wrs[i];
    float base_reg = px - pm - __logf(psum);   // prior_reg; loop-carried in reg

    // ---- prologue: obsv for t=0 (asm, drained pre-loop) + step-0 scalars ----
    float obsv;
    {
        int ov0 = (obs_l[0] * SS + s) * 4;
        asm volatile("global_load_dword %0, %1, %2"
                     : "=v"(obsv) : "v"(ov0), "s"((const void*)obsT));
        asm volatile("s_waitcnt vmcnt(0)");
        __builtin_amdgcn_sched_barrier(0);
    }
    int a_cur = __builtin_amdgcn_readfirstlane(act_l[0]);
    float r_cur = rew_l[0];
    float d_cur = done_l[0];
    int onx_cur = (obs_l[1] * SS + s) * 4;

    float log_prob = 0.f;
    float was_done = 0.f;

    for (int t = 0; t < TT; ++t) {
        const unsigned char* PBa = PB + (size_t)a_cur * (16 * 16384);

        // ---- issue burst: obsv_next + 32 fragment loads (volatile asm) ----
        float obsv_next;
        asm volatile("global_load_dword %0, %1, %2"
                     : "=v"(obsv_next) : "v"(onx_cur), "s"((const void*)obsT));
        ll2 fA[16], fB[16];
#pragma unroll
        for (int c = 0; c < 16; ++c) {
            asm volatile("global_load_dwordx4 %0, %2, %3\n\t"
                         "global_load_dwordx4 %1, %2, %3 offset:1024"
                         : "=v"(fA[c]), "=v"(fB[c])
                         : "v"(wvl16), "s"((const void*)(PBa + (size_t)c * 16384)));
        }

        // ---- phase A: emission + action term + block softmax ----
        const float done = fmaxf(was_done, d_cur);
        float diff = (r_cur - rm) * inv_sig;
        float emis = obsv - 0.5f * diff * diff - rls - 0.5f * LOG2PI;
        float la = la16[0];
#pragma unroll
        for (int i = 1; i < 16; ++i) la = (a_cur == i) ? la16[i] : la;
        if (done == 1.0f || reg == 1.0f) la = 0.f;
        float lq = base_reg + emis + la;

        float wmax = bflyMax(lq);
        if (lane == 0) wrm[wv] = wmax;

        // prefetch next-step scalars (hidden under the reduction barriers)
        const int tn1 = (t + 1 < TT) ? (t + 1) : (TT - 1);
        const int tn2 = (t + 2 <= TT) ? (t + 2) : TT;
        int a_nxt = __builtin_amdgcn_readfirstlane(act_l[tn1]);
        float r_nxt = rew_l[t + 1];
        float d_nxt = done_l[t + 1];
        int onx_nxt = (obs_l[tn2] * SS + s) * 4;

        lds_barrier();  // B1
        float m = wrm[0];
#pragma unroll
        for (int i = 1; i < 8; ++i) m = fmaxf(m, wrm[i]);

        float exv = __expf(lq - m);
        p8[p8idx] = (unsigned char)f32_to_e4m3(exv * 16.0f);
        float wsum = bflySum(exv);
        if (lane == 0) wrs[wv] = wsum;
        lds_barrier();  // B2 (publishes p8)
        float sum = wrs[0];
#pragma unroll
        for (int i = 1; i < 8; ++i) sum += wrs[i];
        float lse = m + __logf(sum);
        float lq_orda = lse * (1.0f - was_done);
        if (!isinf(log_prob)) log_prob += lq_orda;
        was_done = done;

        // ---- phase B: batch the p8 ds_reads, then 16 waited MFMA chunks ----
        const float basev = m - lq_orda - LOG4096;
        long long af16[16];
#pragma unroll
        for (int c = 0; c < 16; ++c)
            af16[c] = *(const long long*)(p8 + quad * 144 + c * 8);

        f32x4 acc0 = {0.f, 0.f, 0.f, 0.f};
        f32x4 acc1 = {0.f, 0.f, 0.f, 0.f};
        f32x4 acc2 = {0.f, 0.f, 0.f, 0.f};
        f32x4 acc3 = {0.f, 0.f, 0.f, 0.f};

#define CHUNK(c, n)                                                             \
        asm volatile("s_waitcnt vmcnt(" #n ")");                                \
        __builtin_amdgcn_sched_barrier(0);                                      \
        acc0 = __builtin_amdgcn_mfma_f32_16x16x32_fp8_fp8((long)fA[c].x, (long)af16[c], acc0, 0, 0, 0); \
        acc1 = __builtin_amdgcn_mfma_f32_16x16x32_fp8_fp8((long)fA[c].y, (long)af16[c], acc1, 0, 0, 0); \
        acc2 = __builtin_amdgcn_mfma_f32_16x16x32_fp8_fp8((long)fB[c].x, (long)af16[c], acc2, 0, 0, 0); \
        acc3 = __builtin_amdgcn_mfma_f32_16x16x32_fp8_fp8((long)fB[c].y, (long)af16[c], acc3, 0, 0, 0);

        CHUNK(0, 30)  CHUNK(1, 28)  CHUNK(2, 26)  CHUNK(3, 24)
        CHUNK(4, 22)  CHUNK(5, 20)  CHUNK(6, 18)  CHUNK(7, 16)
        CHUNK(8, 14)  CHUNK(9, 12)  CHUNK(10, 10) CHUNK(11, 8)
        CHUNK(12, 6)  CHUNK(13, 4)  CHUNK(14, 2)  CHUNK(15, 0)
#undef CHUNK

        // ---- register-only handoff: state wv*64+16q+l = acc_q[0] @ lane l ----
        float t0 = __shfl(acc0[0], lane & 15);
        float t1 = __shfl(acc1[0], lane & 15);
        float t2 = __shfl(acc2[0], lane & 15);
        float t3 = __shfl(acc3[0], lane & 15);
        float av = quad == 0 ? t0 : (quad == 1 ? t1 : (quad == 2 ? t2 : t3));
        base_reg = basev + __logf(av);
        obsv = obsv_next;   // guaranteed landed by CHUNK(15)'s vmcnt(0)
        a_cur = a_nxt; r_cur = r_nxt; d_cur = d_nxt; onx_cur = onx_nxt;
    }

    // final step t = TT (no action term, no transition)
    {
        const float r = rew_l[TT];
        float diff = (r - rm) * inv_sig;
        float emis = obsv - 0.5f * diff * diff - rls - 0.5f * LOG2PI;
        float lq = base_reg + emis;
        float wmax = bflyMax(lq);
        if (lane == 0) wrm[wv] = wmax;
        lds_barrier();
        float m = wrm[0];
#pragma unroll
        for (int i = 1; i < 8; ++i) m = fmaxf(m, wrm[i]);
        float wsum = bflySum(__expf(lq - m));
        if (lane == 0) wrs[wv] = wsum;
        lds_barrier();
        float sum = wrs[0];
#pragma unroll
        for (int i = 1; i < 8; ++i) sum += wrs[i];
        float lse = m + __logf(sum);
        float lq_ord = lse * (1.0f - was_done);
        if (!isinf(log_prob)) log_prob += lq_ord;
    }

    if (tid == 0) out[b] = log_prob;
}

// ---------------- launch ----------------
extern "C" void kernel_launch(void* const* d_in, const int* in_sizes, int n_in,
                              void* d_out, int out_size, void* d_ws, size_t ws_size,
                              hipStream_t stream) {
    const float* regime = (const float*)d_in[0];
    const int* obs = (const int*)d_in[1];
    const float* rewards = (const float*)d_in[2];
    const float* dones = (const float*)d_in[3];
    const int* actions = (const int*)d_in[4];
    const float* prior_logits = (const float*)d_in[5];
    const float* trans_logits = (const float*)d_in[6];
    const float* obs_logits = (const float*)d_in[7];
    const float* policy_logits = (const float*)d_in[8];
    const float* r_mu = (const float*)d_in[9];
    const float* r_logsig = (const float*)d_in[10];
    float* out = (float*)d_out;

    char* ws = (char*)d_ws;
    unsigned char* PB = (unsigned char*)ws;                    // A*S*S fp8 = 4 MB
    float* obsT = (float*)(ws + (size_t)AA * SS * SS);         // O*S fp32 = 8 MB
    float* mo = (float*)(ws + (size_t)AA * SS * SS + (size_t)OO * SS * 4);  // S
    float* lo = mo + SS;                                       // S

    k_pack<<<256, 1024, 0, stream>>>(trans_logits, PB);
    k_obs_stats<<<SS, 256, 0, stream>>>(obs_logits, mo, lo);
    k_obsT<<<(OO / 64) * (SS / 64), 256, 0, stream>>>(obs_logits, mo, lo, obsT);
    k_main<<<BB, 512, 0, stream>>>(regime, obs, rewards, dones, actions, prior_logits,
                                   PB, obsT, policy_logits, r_mu, r_logsig, out);
}